// Round 13
// baseline (119.201 us; speedup 1.0000x reference)
//
#include <hip/hip_runtime.h>
#include <math.h>

// Problem constants (reference: B=4, N=2048, H=5, L=3)
#define B_ 4
#define N_ 2048
#define H_ 5
#define L_ 3
#define EPS_ 1e-6f

constexpr int THREADS = 1024;
constexpr int WAVES = 16;           // 16 waves = 4/SIMD on one CU
constexpr int JPT = N_ / THREADS;   // 2 contiguous elements per thread
constexpr int M_ = 12;              // Taylor terms m = 0..11
constexpr float LOG2E = 1.4426950408889634f;

// 1/m! for m=0..11
__device__ __constant__ float INV_FACT[M_] = {
    1.0f, 1.0f, 0.5f, 1.6666666666666666e-01f, 4.1666666666666664e-02f,
    8.3333333333333332e-03f, 1.3888888888888889e-03f, 1.9841269841269841e-04f,
    2.4801587301587302e-05f, 2.7557319223985893e-06f, 2.7557319223985888e-07f,
    2.5052108385441720e-08f};

// Whole 3-layer encoder: ONE dispatch, 4 blocks (one per batch row), ZERO
// inter-block communication. Rank-1 Taylor factorization:
//   e^{q_i k_j} = sum_m (q_i^m/m!) k_j^m
//   D_i = sum_m (q_i^m/m!) S_m,  S_m = sum_j k_j^m
//   N_i = sum_m (q_i^m/m!) T_m,  T_m = sum_j k_j^m v_j
//   att_i = (N_i - e_ii v_i)/D_i   (exact diagonal zeroing)
// R12 lesson: at 256 threads this is HBM-latency-serialized (VALUBusy 0.3%).
// Fix: 1024 threads (4 waves/SIMD) + software-pipelined head loop -- next
// head's wk/wv/wq loads are issued BEFORE the current head's reduce+barriers,
// so the butterfly covers the load latency.
__global__ __launch_bounds__(THREADS) void encoder_kernel(
    const float* __restrict__ x,      // [B,N]
    const float* __restrict__ WQ,     // [L,H,N]
    const float* __restrict__ WK,     // [L,H,N]
    const float* __restrict__ WV,     // [L,H,N]
    const float* __restrict__ W0,     // [L,H]
    const float* __restrict__ gamma,  // [N]
    const float* __restrict__ beta,   // [N]
    float* __restrict__ out)          // [B,N]
{
  __shared__ float red[WAVES][2 * M_];  // per-wave power-sum partials
  __shared__ float fin[2 * M_];         // folded S'_m, T'_m (1/m! applied)
  __shared__ float2 red2[WAVES];        // LN stat partials

  const int b = blockIdx.x;
  const int tid = threadIdx.x;
  const int wave = tid >> 6;
  const int lane = tid & 63;
  const int e0 = tid * JPT;             // first owned element (float2-aligned)

  // Residual slice + LN params in registers for the whole kernel
  float2 xr = *reinterpret_cast<const float2*>(x + b * N_ + e0);
  const float2 gr = *reinterpret_cast<const float2*>(gamma + e0);
  const float2 br = *reinterpret_cast<const float2*>(beta + e0);

  for (int l = 0; l < L_; ++l) {
    const float* wqL = WQ + l * H_ * N_;
    const float* wkL = WK + l * H_ * N_;
    const float* wvL = WV + l * H_ * N_;

    float2 asum = make_float2(0.f, 0.f);

    // Prologue: prefetch head 0 weights
    float2 wk2 = *reinterpret_cast<const float2*>(wkL + e0);
    float2 wv2 = *reinterpret_cast<const float2*>(wvL + e0);
    float2 wq2 = *reinterpret_cast<const float2*>(wqL + e0);

    for (int h = 0; h < H_; ++h) {
      // ---- k,v for owned elements from prefetched weights ----
      const float k0 = xr.x * wk2.x, k1 = xr.y * wk2.y;
      const float v0 = xr.x * wv2.x, v1 = xr.y * wv2.y;
      const float q0 = xr.x * wq2.x, q1 = xr.y * wq2.y;

      // ---- Issue NEXT head's prefetch (latency hides under reduce) ----
      if (h + 1 < H_) {
        wk2 = *reinterpret_cast<const float2*>(wkL + (h + 1) * N_ + e0);
        wv2 = *reinterpret_cast<const float2*>(wvL + (h + 1) * N_ + e0);
        wq2 = *reinterpret_cast<const float2*>(wqL + (h + 1) * N_ + e0);
      }

      // ---- Power sums S_m, T_m (2 owned elements) ----
      float S[M_], T[M_];
      float p0 = 1.f, p1 = 1.f;
#pragma unroll
      for (int m = 0; m < M_; ++m) {
        S[m] = p0 + p1;
        T[m] = fmaf(p0, v0, p1 * v1);
        p0 *= k0;
        p1 *= k1;
      }

      // ---- Reduce 24 values: butterfly -> LDS -> fold 1/m! ----
#pragma unroll
      for (int m = 0; m < M_; ++m) {
#pragma unroll
        for (int off = 32; off; off >>= 1) {
          S[m] += __shfl_xor(S[m], off);
          T[m] += __shfl_xor(T[m], off);
        }
        if (lane == 0) {
          red[wave][m] = S[m];
          red[wave][M_ + m] = T[m];
        }
      }
      __syncthreads();
      if (tid < 2 * M_) {
        float f = 0.f;
#pragma unroll
        for (int w = 0; w < WAVES; ++w) f += red[w][tid];
        fin[tid] = f * INV_FACT[tid < M_ ? tid : tid - M_];
      }
      __syncthreads();

      float Sf[M_], Tf[M_];
#pragma unroll
      for (int m = 0; m < M_; ++m) {
        Sf[m] = fin[m];
        Tf[m] = fin[M_ + m];
      }
      __syncthreads();  // fin/red free for next head

      // ---- Row phase: poly eval on 2 owned rows, accumulate w0*att ----
      const float w0h = W0[l * H_ + h];
      {
        float d0 = 0.f, n0 = 0.f, pq0 = 1.f;
        float d1 = 0.f, n1 = 0.f, pq1 = 1.f;
#pragma unroll
        for (int m = 0; m < M_; ++m) {
          d0 = fmaf(pq0, Sf[m], d0);
          n0 = fmaf(pq0, Tf[m], n0);
          pq0 *= q0;
          d1 = fmaf(pq1, Sf[m], d1);
          n1 = fmaf(pq1, Tf[m], n1);
          pq1 *= q1;
        }
        const float e0i = __builtin_amdgcn_exp2f(q0 * k0 * LOG2E);
        const float e1i = __builtin_amdgcn_exp2f(q1 * k1 * LOG2E);
        asum.x = fmaf(w0h, (n0 - e0i * v0) * __builtin_amdgcn_rcpf(d0), asum.x);
        asum.y = fmaf(w0h, (n1 - e1i * v1) * __builtin_amdgcn_rcpf(d1), asum.y);
      }
    }

    // ---- Block-local LayerNorm over asum + residual update ----
    float s1 = asum.x + asum.y;
    float s2 = fmaf(asum.x, asum.x, asum.y * asum.y);
#pragma unroll
    for (int off = 32; off; off >>= 1) {
      s1 += __shfl_xor(s1, off);
      s2 += __shfl_xor(s2, off);
    }
    if (lane == 0) red2[wave] = make_float2(s1, s2);
    __syncthreads();
    s1 = 0.f;
    s2 = 0.f;
#pragma unroll
    for (int w = 0; w < WAVES; ++w) {
      s1 += red2[w].x;
      s2 += red2[w].y;
    }
    const float mean = s1 * (1.f / N_);
    const float var = (s2 - s1 * mean) * (1.f / (N_ - 1));
    const float inv = 1.f / (sqrtf(var) + EPS_);
    xr.x += gr.x * (asum.x - mean) * inv + br.x;
    xr.y += gr.y * (asum.y - mean) * inv + br.y;
    __syncthreads();  // red2 free for next layer
  }

  // ---- Write final residual (coalesced float2 per thread) ----
  *reinterpret_cast<float2*>(out + b * N_ + e0) = xr;
}

extern "C" void kernel_launch(void* const* d_in, const int* in_sizes, int n_in,
                              void* d_out, int out_size, void* d_ws, size_t ws_size,
                              hipStream_t stream) {
  const float* x     = (const float*)d_in[0];
  const float* WQ    = (const float*)d_in[1];
  const float* WK    = (const float*)d_in[2];
  const float* WV    = (const float*)d_in[3];
  const float* W0    = (const float*)d_in[4];
  const float* gamma = (const float*)d_in[5];
  const float* beta  = (const float*)d_in[6];
  float* out = (float*)d_out;

  encoder_kernel<<<B_, THREADS, 0, stream>>>(
      x, WQ, WK, WV, W0, gamma, beta, out);
}

// Round 14
// 38.314 us; speedup vs baseline: 3.1112x; 3.1112x over previous
//
#include <hip/hip_runtime.h>
#include <math.h>

// Problem constants (reference: B=4, N=2048, H=5, L=3)
#define B_ 4
#define N_ 2048
#define H_ 5
#define L_ 3
#define EPS_ 1e-6f

constexpr int THREADS = 512;
constexpr int WAVES = 8;            // 2 waves/SIMD on one CU
constexpr int JPT = N_ / THREADS;   // 4 contiguous elements per thread
constexpr int M_ = 12;              // Taylor terms m = 0..11
constexpr float LOG2E = 1.4426950408889634f;

// 1/m! for m=0..11
__device__ __constant__ float INV_FACT[M_] = {
    1.0f, 1.0f, 0.5f, 1.6666666666666666e-01f, 4.1666666666666664e-02f,
    8.3333333333333332e-03f, 1.3888888888888889e-03f, 1.9841269841269841e-04f,
    2.4801587301587302e-05f, 2.7557319223985893e-06f, 2.7557319223985888e-07f,
    2.5052108385441720e-08f};

// Per-wave private power-sum accumulation over [base, base+ITERS*64) of the
// row: S_m += k^m, T_m += k^m * v. No cross-thread communication here.
template <int ITERS>
__device__ __forceinline__ void power_sums(
    const float* __restrict__ xb, const float* __restrict__ wkh,
    const float* __restrict__ wvh, int base, int lane, float* S, float* T) {
#pragma unroll
  for (int m = 0; m < M_; ++m) { S[m] = 0.f; T[m] = 0.f; }
#pragma unroll 8
  for (int i = 0; i < ITERS; ++i) {
    const int j = base + i * 64 + lane;
    const float xv = xb[j];
    const float k = xv * wkh[j];
    const float v = xv * wvh[j];
    float p = 1.f;
#pragma unroll
    for (int m = 0; m < M_; ++m) {
      S[m] += p;
      T[m] = fmaf(p, v, T[m]);
      p *= k;
    }
  }
}

// Whole 3-layer encoder: ONE dispatch, 4 blocks (one per batch row), ZERO
// inter-block communication. Rank-1 Taylor factorization (see R10):
//   att_i = (sum_m q_i^m/m! T_m  -  e_ii v_i) / (sum_m q_i^m/m! S_m)
// R13 lesson: per-head butterfly+barrier cadence (240 butterflies, 45
// barriers) owned the kernel. Here each WAVE privately sums one head's
// S/T over the row (heads 0-2: two waves, half-row each; heads 3-4: one
// wave) -> ONE butterfly per wave per layer, 4 barriers/layer total.
__global__ __launch_bounds__(THREADS) void encoder_kernel(
    const float* __restrict__ x,      // [B,N]
    const float* __restrict__ WQ,     // [L,H,N]
    const float* __restrict__ WK,     // [L,H,N]
    const float* __restrict__ WV,     // [L,H,N]
    const float* __restrict__ W0,     // [L,H]
    const float* __restrict__ gamma,  // [N]
    const float* __restrict__ beta,   // [N]
    float* __restrict__ out)          // [B,N]
{
  __shared__ float xb[N_];            // residual row (8 KB)
  __shared__ float STp[WAVES][32];    // per-wave S(0..11)/T(12..23) partials
  __shared__ float fin[H_][32];       // folded S'/T' per head (1/m! applied)
  __shared__ float2 red2[WAVES];      // LN stat partials

  const int b = blockIdx.x;
  const int tid = threadIdx.x;
  const int wave = tid >> 6;
  const int lane = tid & 63;
  const int e0 = tid * JPT;           // 4 contiguous owned elements

  // Wave -> (head, row-range) assignment for the power phase
  const int phead = (wave < 5) ? wave : wave - 5;   // waves 5-7 help heads 0-2
  const int pbase = (wave < 5) ? 0 : 1024;

  // Residual slice + LN params in registers for the whole kernel
  float xr[JPT], gr[JPT], br[JPT];
  {
    float4 t = *reinterpret_cast<const float4*>(x + b * N_ + e0);
    xr[0] = t.x; xr[1] = t.y; xr[2] = t.z; xr[3] = t.w;
    t = *reinterpret_cast<const float4*>(gamma + e0);
    gr[0] = t.x; gr[1] = t.y; gr[2] = t.z; gr[3] = t.w;
    t = *reinterpret_cast<const float4*>(beta + e0);
    br[0] = t.x; br[1] = t.y; br[2] = t.z; br[3] = t.w;
  }
  *reinterpret_cast<float4*>(xb + e0) =
      make_float4(xr[0], xr[1], xr[2], xr[3]);
  __syncthreads();

  for (int l = 0; l < L_; ++l) {
    // ---- Power phase: wave-private S/T over assigned row range ----
    const float* wkh = WK + (l * H_ + phead) * N_;
    const float* wvh = WV + (l * H_ + phead) * N_;
    float S[M_], T[M_];
    if (phead < 3)
      power_sums<16>(xb, wkh, wvh, pbase, lane, S, T);   // half row
    else
      power_sums<32>(xb, wkh, wvh, 0, lane, S, T);       // full row

    // One 24-value butterfly per wave per layer
#pragma unroll
    for (int m = 0; m < M_; ++m) {
#pragma unroll
      for (int off = 32; off; off >>= 1) {
        S[m] += __shfl_xor(S[m], off);
        T[m] += __shfl_xor(T[m], off);
      }
    }
    if (lane == 0) {
#pragma unroll
      for (int m = 0; m < M_; ++m) {
        STp[wave][m] = S[m];
        STp[wave][12 + m] = T[m];
      }
    }
    __syncthreads();  // B1: STp ready

    // ---- Fold: combine wave partials per head, apply 1/m! ----
    if (tid < 160) {
      const int h = tid >> 5, m = tid & 31;
      if (m < 24) {
        float f = STp[h][m];
        if (h < 3) f += STp[h + 5][m];
        fin[h][m] = f * INV_FACT[m < 12 ? m : m - 12];
      }
    }
    __syncthreads();  // B2: fin ready

    // ---- Row phase: all 5 heads' polynomials on 4 owned elements ----
    float asum[JPT] = {0.f, 0.f, 0.f, 0.f};
    for (int h = 0; h < H_; ++h) {
      float Sf[M_], Tf[M_];
#pragma unroll
      for (int m = 0; m < M_; ++m) {
        Sf[m] = fin[h][m];
        Tf[m] = fin[h][12 + m];
      }
      float4 wq4 = *reinterpret_cast<const float4*>(WQ + (l * H_ + h) * N_ + e0);
      float4 wk4 = *reinterpret_cast<const float4*>(WK + (l * H_ + h) * N_ + e0);
      float4 wv4 = *reinterpret_cast<const float4*>(WV + (l * H_ + h) * N_ + e0);
      const float wqa[4] = {wq4.x, wq4.y, wq4.z, wq4.w};
      const float wka[4] = {wk4.x, wk4.y, wk4.z, wk4.w};
      const float wva[4] = {wv4.x, wv4.y, wv4.z, wv4.w};
      const float w0h = W0[l * H_ + h];
#pragma unroll
      for (int u = 0; u < JPT; ++u) {
        const float q = xr[u] * wqa[u];
        const float k = xr[u] * wka[u];
        const float v = xr[u] * wva[u];
        float d = 0.f, n = 0.f, pq = 1.f;
#pragma unroll
        for (int m = 0; m < M_; ++m) {
          d = fmaf(pq, Sf[m], d);
          n = fmaf(pq, Tf[m], n);
          pq *= q;
        }
        const float eii = __builtin_amdgcn_exp2f(q * k * LOG2E);
        asum[u] = fmaf(w0h, (n - eii * v) * __builtin_amdgcn_rcpf(d), asum[u]);
      }
    }

    // ---- Block-local LayerNorm + residual update ----
    float s1 = 0.f, s2 = 0.f;
#pragma unroll
    for (int u = 0; u < JPT; ++u) {
      s1 += asum[u];
      s2 = fmaf(asum[u], asum[u], s2);
    }
#pragma unroll
    for (int off = 32; off; off >>= 1) {
      s1 += __shfl_xor(s1, off);
      s2 += __shfl_xor(s2, off);
    }
    if (lane == 0) red2[wave] = make_float2(s1, s2);
    __syncthreads();  // B3: red2 ready
    s1 = 0.f; s2 = 0.f;
#pragma unroll
    for (int w = 0; w < WAVES; ++w) {
      s1 += red2[w].x;
      s2 += red2[w].y;
    }
    const float mean = s1 * (1.f / N_);
    const float var = (s2 - s1 * mean) * (1.f / (N_ - 1));
    const float inv = 1.f / (sqrtf(var) + EPS_);
#pragma unroll
    for (int u = 0; u < JPT; ++u) {
      xr[u] += gr[u] * (asum[u] - mean) * inv + br[u];
    }

    if (l + 1 < L_) {
      *reinterpret_cast<float4*>(xb + e0) =
          make_float4(xr[0], xr[1], xr[2], xr[3]);
      __syncthreads();  // B4: xb ready for next layer's power phase
    }
  }

  // ---- Write final residual (coalesced float4) ----
  *reinterpret_cast<float4*>(out + b * N_ + e0) =
      make_float4(xr[0], xr[1], xr[2], xr[3]);
}

extern "C" void kernel_launch(void* const* d_in, const int* in_sizes, int n_in,
                              void* d_out, int out_size, void* d_ws, size_t ws_size,
                              hipStream_t stream) {
  const float* x     = (const float*)d_in[0];
  const float* WQ    = (const float*)d_in[1];
  const float* WK    = (const float*)d_in[2];
  const float* WV    = (const float*)d_in[3];
  const float* W0    = (const float*)d_in[4];
  const float* gamma = (const float*)d_in[5];
  const float* beta  = (const float*)d_in[6];
  float* out = (float*)d_out;

  encoder_kernel<<<B_, THREADS, 0, stream>>>(
      x, WQ, WK, WV, W0, gamma, beta, out);
}